// Round 1
// baseline (680.928 us; speedup 1.0000x reference)
//
#include <hip/hip_runtime.h>
#include <math.h>

#define NFFT    1024
#define HOP     256
#define NMELS   128
#define NFRAMES 626
#define NPAIRS  313
#define NBATCH  32
#define LSAMP   160000
#define NFREQ   513   // NFFT/2 + 1

// reflect-pad index (np.pad mode='reflect', no edge repeat)
__device__ __forceinline__ int refl(int i) {
    if (i < 0) i = -i;
    else if (i >= LSAMP) i = 2 * LSAMP - 2 - i;
    return i;
}

// One block = one frame pair (frames 2p, 2p+1) of one batch row.
// Two-for-one real FFT: z[n] = frame0[n] + i*frame1[n], 1024-pt complex
// Stockham radix-2 FFT in LDS, then unpack + magnitude + mel projection.
__global__ __launch_bounds__(256)
void fft_mel_kernel(const float* __restrict__ x, const float* __restrict__ fb,
                    float* __restrict__ mel) {
    __shared__ float2 bufA[1024];
    __shared__ float2 bufB[1024];
    __shared__ float2 tw[512];          // W[r] = exp(-i*pi*r/512)
    __shared__ float  spec[2][NFREQ];

    const int tid = threadIdx.x;
    const int p   = blockIdx.x;         // frame pair index, 0..312
    const int b   = blockIdx.y;         // batch row

    // Build twiddle table (once per block)
    for (int r = tid; r < 512; r += 256) {
        float s, c;
        sincosf(-(float)M_PI * (float)r * (1.0f / 512.0f), &s, &c);
        tw[r] = make_float2(c, s);
    }

    // Load frame pair with reflect padding.
    // frame f covers x[f*HOP - 512 + n], n in [0,1024)
    const float* xb = x + (size_t)b * LSAMP;
    const int base = 512 * p - 512;     // start of frame 2p in x coords
    for (int i = tid; i < 1024; i += 256) {
        float re = xb[refl(base + i)];
        float im = xb[refl(base + i + 256)];
        bufA[i] = make_float2(re, im);
    }

    // Stockham radix-2, 10 stages, ping-pong. After 10 swaps result is in bufA.
    float2* X = bufA;
    float2* Y = bufB;
    for (int s = 0; s < 10; s++) {
        const int m = 1 << s;
        __syncthreads();
        #pragma unroll
        for (int u = 0; u < 2; u++) {
            const int t  = tid + u * 256;     // butterfly id, 0..511
            const int jm = t & ~(m - 1);      // m*j  (also the twiddle index)
            float2 a = X[t];
            float2 c = X[t + 512];
            float2 w = tw[jm];
            float dr = a.x - c.x, di = a.y - c.y;
            const int w0 = t + jm;            // k + 2*m*j
            Y[w0]     = make_float2(a.x + c.x, a.y + c.y);
            Y[w0 + m] = make_float2(dr * w.x - di * w.y, dr * w.y + di * w.x);
        }
        float2* tmp = X; X = Y; Y = tmp;
    }
    __syncthreads();

    // Unpack two-for-one and take magnitudes.
    // X1[k] = 0.5*(Z[k] + conj(Z[N-k])), X2[k] = -0.5i*(Z[k] - conj(Z[N-k]))
    for (int k = tid; k < NFREQ; k += 256) {
        const int nk = (1024 - k) & 1023;
        float2 Zk = X[k], Zn = X[nk];
        float ar = Zk.x + Zn.x, ai = Zk.y - Zn.y;
        float br = Zk.y + Zn.y, bi = Zn.x - Zk.x;
        spec[0][k] = 0.5f * sqrtf(ar * ar + ai * ai);
        spec[1][k] = 0.5f * sqrtf(br * br + bi * bi);
    }
    __syncthreads();

    // Mel projection: thread -> (which frame of pair, mel channel)
    const int pf = tid >> 7;
    const int m  = tid & 127;
    const float* sp = spec[pf];
    float acc = 0.f;
    #pragma unroll 8
    for (int f = 0; f < NFREQ; f++) {
        acc = fmaf(sp[f], fb[f * NMELS + m], acc);
    }
    mel[((size_t)b * NFRAMES + 2 * p + pf) * NMELS + m] = acc;
}

// Streaming PCEN: one thread per (batch, mel) sequence, sequential EMA over t.
__global__ __launch_bounds__(256)
void pcen_kernel(const float* __restrict__ mel, float* __restrict__ out) {
    const int idx = blockIdx.x * 256 + threadIdx.x;   // 0..4095
    const int b = idx >> 7;
    const int m = idx & 127;
    const float* mp = mel + (size_t)b * NFRAMES * NMELS + m;
    float*       op = out + (size_t)b * NFRAMES * NMELS + m;
    float M = 0.f;
    for (int t = 0; t < NFRAMES; t++) {
        float v = mp[(size_t)t * NMELS];
        M = (t == 0) ? v : fmaf(0.975f, M, 0.025f * v);   // (1-S)*M + S*v
        float den = __powf(M + 1e-6f, 0.98f);
        float r = v / den;
        op[(size_t)t * NMELS] = sqrtf(r + 2.0f) - 1.41421356237f;  // ^0.5 - 2^0.5
    }
}

extern "C" void kernel_launch(void* const* d_in, const int* in_sizes, int n_in,
                              void* d_out, int out_size, void* d_ws, size_t ws_size,
                              hipStream_t stream) {
    const float* x  = (const float*)d_in[0];   // (32, 160000)
    const float* fb = (const float*)d_in[1];   // (513, 128)
    float* mel = (float*)d_ws;                 // (32, 626, 128) = 10.25 MB scratch
    float* out = (float*)d_out;                // (32, 626, 128)

    dim3 grid1(NPAIRS, NBATCH);
    fft_mel_kernel<<<grid1, 256, 0, stream>>>(x, fb, mel);

    pcen_kernel<<<(NBATCH * NMELS) / 256, 256, 0, stream>>>(mel, out);
}

// Round 2
// 154.160 us; speedup vs baseline: 4.4170x; 4.4170x over previous
//
#include <hip/hip_runtime.h>
#include <math.h>

#define NFFT    1024
#define HOP     256
#define NMELS   128
#define NFRAMES 626
#define NPAIRS  313
#define NBATCH  32
#define LSAMP   160000
#define NFREQ   513   // NFFT/2 + 1

#define PCEN_C  32    // outputs per pcen thread
#define PCEN_W  256   // warmup frames (0.975^256 = 1.5e-3 residual of init error)
#define NCHUNK  ((NFRAMES + PCEN_C - 1) / PCEN_C)   // 20

struct Bins { int v[NMELS + 2]; };   // 130 ints = 520 B kernarg

// reflect-pad index (np.pad mode='reflect', no edge repeat)
__device__ __forceinline__ int refl(int i) {
    if (i < 0) i = -i;
    else if (i >= LSAMP) i = 2 * LSAMP - 2 - i;
    return i;
}

// One block = one frame pair (frames 2p, 2p+1) of one batch row.
// Two-for-one real FFT: z[n] = frame0[n] + i*frame1[n], 1024-pt complex
// Stockham radix-2 FFT in LDS, then unpack + magnitude + sparse mel projection
// (triangular filterbank weights synthesized on-device from bin edges).
__global__ __launch_bounds__(256)
void fft_mel_kernel(const float* __restrict__ x, float* __restrict__ mel,
                    Bins bins) {
    __shared__ float2 bufA[1024];
    __shared__ float2 bufB[1024];
    __shared__ float2 tw[512];          // W[r] = exp(-i*pi*r/512)
    __shared__ float  spec[2][NFREQ];

    const int tid = threadIdx.x;
    const int p   = blockIdx.x;         // frame pair index, 0..312
    const int b   = blockIdx.y;         // batch row

    // Build twiddle table (once per block)
    for (int r = tid; r < 512; r += 256) {
        float s, c;
        __sincosf(-(float)M_PI * (float)r * (1.0f / 512.0f), &s, &c);
        tw[r] = make_float2(c, s);
    }

    // Load frame pair with reflect padding.
    // frame f covers x[f*HOP - 512 + n], n in [0,1024)
    const float* xb = x + (size_t)b * LSAMP;
    const int base = 512 * p - 512;     // start of frame 2p in x coords
    for (int i = tid; i < 1024; i += 256) {
        float re = xb[refl(base + i)];
        float im = xb[refl(base + i + 256)];
        bufA[i] = make_float2(re, im);
    }

    // Stockham radix-2, 10 stages, ping-pong. After 10 swaps result is in bufA.
    float2* X = bufA;
    float2* Y = bufB;
    for (int s = 0; s < 10; s++) {
        const int m = 1 << s;
        __syncthreads();
        #pragma unroll
        for (int u = 0; u < 2; u++) {
            const int t  = tid + u * 256;     // butterfly id, 0..511
            const int jm = t & ~(m - 1);      // m*j  (also the twiddle index)
            float2 a = X[t];
            float2 c = X[t + 512];
            float2 w = tw[jm];
            float dr = a.x - c.x, di = a.y - c.y;
            const int w0 = t + jm;            // k + 2*m*j
            Y[w0]     = make_float2(a.x + c.x, a.y + c.y);
            Y[w0 + m] = make_float2(dr * w.x - di * w.y, dr * w.y + di * w.x);
        }
        float2* tmp = X; X = Y; Y = tmp;
    }
    __syncthreads();

    // Unpack two-for-one and take magnitudes.
    for (int k = tid; k < NFREQ; k += 256) {
        const int nk = (1024 - k) & 1023;
        float2 Zk = X[k], Zn = X[nk];
        float ar = Zk.x + Zn.x, ai = Zk.y - Zn.y;
        float br = Zk.y + Zn.y, bi = Zn.x - Zk.x;
        spec[0][k] = 0.5f * sqrtf(ar * ar + ai * ai);
        spec[1][k] = 0.5f * sqrtf(br * br + bi * bi);
    }
    __syncthreads();

    // Sparse mel projection: column mm of fb is nonzero only on [a, c) with
    // rising ramp (f-a)/(b-a) on [a,b) and falling ramp (c-f)/(c-b) on [b,c).
    const int pf = tid >> 7;
    const int mm = tid & 127;
    const float* sp = spec[pf];
    const int a = bins.v[mm], bb = bins.v[mm + 1], c = bins.v[mm + 2];
    float acc = 0.f;
    if (bb > a) {
        float s = 0.f;
        for (int f = a; f < bb; f++) s = fmaf(sp[f], (float)(f - a), s);
        acc += s / (float)(bb - a);
    }
    if (c > bb) {
        float s = 0.f;
        for (int f = bb; f < c; f++) s = fmaf(sp[f], (float)(c - f), s);
        acc += s / (float)(c - bb);
    }
    mel[((size_t)b * NFRAMES + 2 * p + pf) * NMELS + mm] = acc;
}

// Chunked-parallel streaming PCEN.
// Thread -> (b, chunk, m); each thread produces PCEN_C outputs after warming
// the EMA over up to PCEN_W preceding frames (0.975^256 decay of init error).
// Chunks with t0 <= PCEN_W start from t=0 and are exact.
__global__ __launch_bounds__(256)
void pcen_kernel(const float* __restrict__ mel, float* __restrict__ out) {
    const int idx  = blockIdx.x * 256 + threadIdx.x;
    const int m    = idx & 127;
    const int rest = idx >> 7;              // wave-uniform
    const int chunk = rest % NCHUNK;
    const int b     = rest / NCHUNK;
    if (b >= NBATCH) return;

    const int t0   = chunk * PCEN_C;
    const int tend = (t0 + PCEN_C < NFRAMES) ? t0 + PCEN_C : NFRAMES;
    const int ts   = (t0 > PCEN_W) ? t0 - PCEN_W : 0;

    const float* mp = mel + (size_t)b * NFRAMES * NMELS + m;
    float*       op = out + (size_t)b * NFRAMES * NMELS + m;

    float M = mp[(size_t)ts * NMELS];       // ts==0: exact init; else approx
    #pragma unroll 8
    for (int t = ts + 1; t < t0; t++) {
        M = fmaf(0.975f, M, 0.025f * mp[(size_t)t * NMELS]);
    }

    int t = t0;
    if (t0 == 0) {                          // t=0: M = v0, no EMA update
        float v = mp[0];
        float den = __powf(M + 1e-6f, 0.98f);
        op[0] = sqrtf(v / den + 2.0f) - 1.41421356237f;
        t = 1;
    }
    #pragma unroll 4
    for (; t < tend; t++) {
        float v = mp[(size_t)t * NMELS];
        M = fmaf(0.975f, M, 0.025f * v);
        float den = __powf(M + 1e-6f, 0.98f);
        op[(size_t)t * NMELS] = sqrtf(v / den + 2.0f) - 1.41421356237f;
    }
}

extern "C" void kernel_launch(void* const* d_in, const int* in_sizes, int n_in,
                              void* d_out, int out_size, void* d_ws, size_t ws_size,
                              hipStream_t stream) {
    const float* x  = (const float*)d_in[0];   // (32, 160000)
    float* mel = (float*)d_ws;                 // (32, 626, 128) = 10.25 MB scratch
    float* out = (float*)d_out;                // (32, 626, 128)

    // Host-side bin edges, replicating numpy exactly in double:
    //   m_pts = linspace(0, 2595*log10(1+8000/700), 130)
    //   f_pts = 700*(10^(m_pts/2595)-1);  bins = floor(1024*f_pts/16000)
    Bins bins;
    {
        const double m_max = 2595.0 * log10(1.0 + 8000.0 / 700.0);
        const double step  = m_max / 129.0;
        for (int i = 0; i < NMELS + 2; i++) {
            double mv = (i == NMELS + 1) ? m_max : (double)i * step;
            double f  = 700.0 * (pow(10.0, mv / 2595.0) - 1.0);
            bins.v[i] = (int)floor((double)(NFREQ - 1) * 2.0 * f / 16000.0);
        }
    }

    dim3 grid1(NPAIRS, NBATCH);
    fft_mel_kernel<<<grid1, 256, 0, stream>>>(x, mel, bins);

    const int nthreads = NBATCH * NMELS * NCHUNK;     // 81920
    pcen_kernel<<<(nthreads + 255) / 256, 256, 0, stream>>>(mel, out);
}

// Round 3
// 133.519 us; speedup vs baseline: 5.0999x; 1.1546x over previous
//
#include <hip/hip_runtime.h>
#include <math.h>

#define NFFT    1024
#define HOP     256
#define NMELS   128
#define NFRAMES 626
#define NPAIRS  313
#define NBATCH  32
#define LSAMP   160000
#define NFREQ   513   // NFFT/2 + 1

#define PCEN_C  16    // outputs per pcen thread
#define PCEN_W  256   // warmup frames (0.975^256 = 1.5e-3 residual of init error)
#define NCHUNK  ((NFRAMES + PCEN_C - 1) / PCEN_C)   // 40

// LDS padding to break power-of-2 write strides (radix-4 stages m=1,4,16)
#define PHYS(i) ((i) + ((i) >> 5))

struct Bins { int v[NMELS + 2]; };   // 130 ints = 520 B kernarg

// reflect-pad index (np.pad mode='reflect', no edge repeat)
__device__ __forceinline__ int refl(int i) {
    if (i < 0) i = -i;
    else if (i >= LSAMP) i = 2 * LSAMP - 2 - i;
    return i;
}

__device__ __forceinline__ float2 cmul(float2 a, float2 b) {
    return make_float2(fmaf(a.x, b.x, -a.y * b.y), fmaf(a.x, b.y, a.y * b.x));
}

// One block = one frame pair (frames 2p, 2p+1) of one batch row.
// Two-for-one real FFT: z[n] = frame0[n] + i*frame1[n], 1024-pt complex
// radix-4 Stockham DIF FFT (5 stages) in padded LDS, then unpack + magnitude
// + sparse mel projection (triangular fb weights synthesized from bin edges).
__global__ __launch_bounds__(256)
void fft_mel_kernel(const float* __restrict__ x, float* __restrict__ mel,
                    Bins bins) {
    __shared__ float2 bufA[1056];       // 1024 + 32 pad
    __shared__ float2 bufB[1056];
    __shared__ float2 tw[256];          // tw[r] = exp(-2*pi*i*r/1024), r<256

    const int tid = threadIdx.x;
    const int p   = blockIdx.x;         // frame pair index, 0..312
    const int b   = blockIdx.y;         // batch row

    // Twiddle table (jm = m*(t/m) < 256 only; W^2jm, W^3jm built in-register)
    {
        float s, c;
        __sincosf(-(float)M_PI * (float)tid * (1.0f / 512.0f), &s, &c);
        tw[tid] = make_float2(c, s);
    }

    // Load frame pair with reflect padding.
    // frame f covers x[f*HOP - 512 + n], n in [0,1024)
    const float* xb = x + (size_t)b * LSAMP;
    const int base = 512 * p - 512;     // start of frame 2p in x coords
    for (int i = tid; i < 1024; i += 256) {
        float re = xb[refl(base + i)];
        float im = xb[refl(base + i + 256)];
        bufA[PHYS(i)] = make_float2(re, im);
    }

    // Radix-4 Stockham DIF, 5 stages (m = 1,4,16,64,256), ping-pong A->B->...
    // Derived by fusing the verified radix-2 stages (m, 2m):
    //   t = k + m*j, reads X[t + 256p], writes Y[t + 3*jm + q*m] = DFT4_q * W^(q*jm)
    float2* X = bufA;
    float2* Y = bufB;
    #pragma unroll
    for (int s = 0; s < 5; s++) {
        const int m  = 1 << (2 * s);
        __syncthreads();
        const int jm = tid & ~(m - 1);
        float2 a0 = X[PHYS(tid)];
        float2 a1 = X[PHYS(tid + 256)];
        float2 a2 = X[PHYS(tid + 512)];
        float2 a3 = X[PHYS(tid + 768)];
        float s02r = a0.x + a2.x, s02i = a0.y + a2.y;
        float d02r = a0.x - a2.x, d02i = a0.y - a2.y;
        float s13r = a1.x + a3.x, s13i = a1.y + a3.y;
        float d13r = a1.x - a3.x, d13i = a1.y - a3.y;
        float2 X0 = make_float2(s02r + s13r, s02i + s13i);
        float2 X1 = make_float2(d02r + d13i, d02i - d13r);   // d02 - i*d13
        float2 X2 = make_float2(s02r - s13r, s02i - s13i);
        float2 X3 = make_float2(d02r - d13i, d02i + d13r);   // d02 + i*d13
        const int ob = tid + 3 * jm;
        if (s == 4) {                    // m=256 -> jm=0 -> identity twiddles
            Y[PHYS(ob)]           = X0;
            Y[PHYS(ob + 256)]     = X1;
            Y[PHYS(ob + 512)]     = X2;
            Y[PHYS(ob + 768)]     = X3;
        } else {
            float2 w1 = tw[jm];
            float2 w2 = make_float2(fmaf(w1.x, w1.x, -w1.y * w1.y),
                                    2.0f * w1.x * w1.y);
            float2 w3 = cmul(w1, w2);
            Y[PHYS(ob)]         = X0;
            Y[PHYS(ob + m)]     = cmul(X1, w1);
            Y[PHYS(ob + 2 * m)] = cmul(X2, w2);
            Y[PHYS(ob + 3 * m)] = cmul(X3, w3);
        }
        float2* tmp = X; X = Y; Y = tmp;
    }
    __syncthreads();

    // spec aliases the dead ping-pong buffer (result lives in bufB; A is free)
    float* spec0 = (float*)bufA;
    float* spec1 = spec0 + NFREQ;

    // Unpack two-for-one and take magnitudes.
    for (int k = tid; k < NFREQ; k += 256) {
        const int nk = (1024 - k) & 1023;
        float2 Zk = X[PHYS(k)], Zn = X[PHYS(nk)];
        float ar = Zk.x + Zn.x, ai = Zk.y - Zn.y;
        float br = Zk.y + Zn.y, bi = Zn.x - Zk.x;
        spec0[k] = 0.5f * sqrtf(ar * ar + ai * ai);
        spec1[k] = 0.5f * sqrtf(br * br + bi * bi);
    }
    __syncthreads();

    // Sparse mel projection: column mm of fb is nonzero only on [a, c) with
    // rising ramp (f-a)/(b-a) on [a,b) and falling ramp (c-f)/(c-b) on [b,c).
    const int pf = tid >> 7;
    const int mm = tid & 127;
    const float* sp = pf ? spec1 : spec0;
    const int a = bins.v[mm], bb = bins.v[mm + 1], c = bins.v[mm + 2];
    float acc = 0.f;
    if (bb > a) {
        float s = 0.f;
        for (int f = a; f < bb; f++) s = fmaf(sp[f], (float)(f - a), s);
        acc += s / (float)(bb - a);
    }
    if (c > bb) {
        float s = 0.f;
        for (int f = bb; f < c; f++) s = fmaf(sp[f], (float)(c - f), s);
        acc += s / (float)(c - bb);
    }
    mel[((size_t)b * NFRAMES + 2 * p + pf) * NMELS + mm] = acc;
}

// Chunked-parallel streaming PCEN.
// Thread -> (b, chunk, m); each thread produces PCEN_C outputs after warming
// the EMA over up to PCEN_W preceding frames (0.975^256 decay of init error).
// Chunks with t0 <= PCEN_W start from t=0 and are exact.
__global__ __launch_bounds__(256)
void pcen_kernel(const float* __restrict__ mel, float* __restrict__ out) {
    const int idx  = blockIdx.x * 256 + threadIdx.x;
    const int m    = idx & 127;
    const int rest = idx >> 7;              // wave-uniform
    const int chunk = rest % NCHUNK;
    const int b     = rest / NCHUNK;
    if (b >= NBATCH) return;

    const int t0   = chunk * PCEN_C;
    const int tend = (t0 + PCEN_C < NFRAMES) ? t0 + PCEN_C : NFRAMES;
    const int ts   = (t0 > PCEN_W) ? t0 - PCEN_W : 0;

    const float* mp = mel + (size_t)b * NFRAMES * NMELS + m;
    float*       op = out + (size_t)b * NFRAMES * NMELS + m;

    float M = mp[(size_t)ts * NMELS];       // ts==0: exact init; else approx
    #pragma unroll 8
    for (int t = ts + 1; t < t0; t++) {
        M = fmaf(0.975f, M, 0.025f * mp[(size_t)t * NMELS]);
    }

    int t = t0;
    if (t0 == 0) {                          // t=0: M = v0, no EMA update
        float v = mp[0];
        float den = __powf(M + 1e-6f, 0.98f);
        op[0] = sqrtf(v / den + 2.0f) - 1.41421356237f;
        t = 1;
    }
    #pragma unroll 4
    for (; t < tend; t++) {
        float v = mp[(size_t)t * NMELS];
        M = fmaf(0.975f, M, 0.025f * v);
        float den = __powf(M + 1e-6f, 0.98f);
        op[(size_t)t * NMELS] = sqrtf(v / den + 2.0f) - 1.41421356237f;
    }
}

extern "C" void kernel_launch(void* const* d_in, const int* in_sizes, int n_in,
                              void* d_out, int out_size, void* d_ws, size_t ws_size,
                              hipStream_t stream) {
    const float* x  = (const float*)d_in[0];   // (32, 160000)
    float* mel = (float*)d_ws;                 // (32, 626, 128) = 10.25 MB scratch
    float* out = (float*)d_out;                // (32, 626, 128)

    // Host-side bin edges, replicating numpy exactly in double:
    //   m_pts = linspace(0, 2595*log10(1+8000/700), 130)
    //   f_pts = 700*(10^(m_pts/2595)-1);  bins = floor(1024*f_pts/16000)
    Bins bins;
    {
        const double m_max = 2595.0 * log10(1.0 + 8000.0 / 700.0);
        const double step  = m_max / 129.0;
        for (int i = 0; i < NMELS + 2; i++) {
            double mv = (i == NMELS + 1) ? m_max : (double)i * step;
            double f  = 700.0 * (pow(10.0, mv / 2595.0) - 1.0);
            bins.v[i] = (int)floor((double)(NFREQ - 1) * 2.0 * f / 16000.0);
        }
    }

    dim3 grid1(NPAIRS, NBATCH);
    fft_mel_kernel<<<grid1, 256, 0, stream>>>(x, mel, bins);

    const int nthreads = NBATCH * NMELS * NCHUNK;     // 163840
    pcen_kernel<<<(nthreads + 255) / 256, 256, 0, stream>>>(mel, out);
}

// Round 4
// 130.901 us; speedup vs baseline: 5.2019x; 1.0200x over previous
//
#include <hip/hip_runtime.h>
#include <math.h>

#define NFFT    1024
#define HOP     256
#define NMELS   128
#define NFRAMES 626
#define NPAIRS  313
#define NBATCH  32
#define LSAMP   160000
#define NFREQ   513   // NFFT/2 + 1

#define PCEN_C  16                                  // frames per chunk
#define NCHUNK  ((NFRAMES + PCEN_C - 1) / PCEN_C)   // 40 (last chunk = 2 frames)

// LDS padding to break power-of-2 write strides (radix-4 stages m=1,4,16)
#define PHYS(i) ((i) + ((i) >> 5))

struct Bins { int v[NMELS + 2]; };   // 130 ints = 520 B kernarg

// reflect-pad index (np.pad mode='reflect', no edge repeat)
__device__ __forceinline__ int refl(int i) {
    if (i < 0) i = -i;
    else if (i >= LSAMP) i = 2 * LSAMP - 2 - i;
    return i;
}

__device__ __forceinline__ float2 cmul(float2 a, float2 b) {
    return make_float2(fmaf(a.x, b.x, -a.y * b.y), fmaf(a.x, b.y, a.y * b.x));
}

// One block = one frame pair (frames 2p, 2p+1) of one batch row.
// Two-for-one real FFT: z[n] = frame0[n] + i*frame1[n], 1024-pt complex
// radix-4 Stockham DIF FFT (5 stages) in padded LDS, then unpack + magnitude
// + sparse mel projection (triangular fb weights synthesized from bin edges).
__global__ __launch_bounds__(256)
void fft_mel_kernel(const float* __restrict__ x, float* __restrict__ mel,
                    Bins bins) {
    __shared__ float2 bufA[1056];       // 1024 + 32 pad
    __shared__ float2 bufB[1056];
    __shared__ float2 tw[256];          // tw[r] = exp(-2*pi*i*r/1024), r<256

    const int tid = threadIdx.x;
    const int p   = blockIdx.x;         // frame pair index, 0..312
    const int b   = blockIdx.y;         // batch row

    // Twiddle table (jm = m*(t/m) < 256 only; W^2jm, W^3jm built in-register)
    {
        float s, c;
        __sincosf(-(float)M_PI * (float)tid * (1.0f / 512.0f), &s, &c);
        tw[tid] = make_float2(c, s);
    }

    // Load frame pair with reflect padding.
    const float* xb = x + (size_t)b * LSAMP;
    const int base = 512 * p - 512;     // start of frame 2p in x coords
    for (int i = tid; i < 1024; i += 256) {
        float re = xb[refl(base + i)];
        float im = xb[refl(base + i + 256)];
        bufA[PHYS(i)] = make_float2(re, im);
    }

    // Radix-4 Stockham DIF, 5 stages (m = 1,4,16,64,256), ping-pong A->B->...
    float2* X = bufA;
    float2* Y = bufB;
    #pragma unroll
    for (int s = 0; s < 5; s++) {
        const int m  = 1 << (2 * s);
        __syncthreads();
        const int jm = tid & ~(m - 1);
        float2 a0 = X[PHYS(tid)];
        float2 a1 = X[PHYS(tid + 256)];
        float2 a2 = X[PHYS(tid + 512)];
        float2 a3 = X[PHYS(tid + 768)];
        float s02r = a0.x + a2.x, s02i = a0.y + a2.y;
        float d02r = a0.x - a2.x, d02i = a0.y - a2.y;
        float s13r = a1.x + a3.x, s13i = a1.y + a3.y;
        float d13r = a1.x - a3.x, d13i = a1.y - a3.y;
        float2 X0 = make_float2(s02r + s13r, s02i + s13i);
        float2 X1 = make_float2(d02r + d13i, d02i - d13r);   // d02 - i*d13
        float2 X2 = make_float2(s02r - s13r, s02i - s13i);
        float2 X3 = make_float2(d02r - d13i, d02i + d13r);   // d02 + i*d13
        const int ob = tid + 3 * jm;
        if (s == 4) {                    // m=256 -> jm=0 -> identity twiddles
            Y[PHYS(ob)]           = X0;
            Y[PHYS(ob + 256)]     = X1;
            Y[PHYS(ob + 512)]     = X2;
            Y[PHYS(ob + 768)]     = X3;
        } else {
            float2 w1 = tw[jm];
            float2 w2 = make_float2(fmaf(w1.x, w1.x, -w1.y * w1.y),
                                    2.0f * w1.x * w1.y);
            float2 w3 = cmul(w1, w2);
            Y[PHYS(ob)]         = X0;
            Y[PHYS(ob + m)]     = cmul(X1, w1);
            Y[PHYS(ob + 2 * m)] = cmul(X2, w2);
            Y[PHYS(ob + 3 * m)] = cmul(X3, w3);
        }
        float2* tmp = X; X = Y; Y = tmp;
    }
    __syncthreads();

    // spec aliases the dead ping-pong buffer (result lives in bufB; A is free)
    float* spec0 = (float*)bufA;
    float* spec1 = spec0 + NFREQ;

    // Unpack two-for-one and take magnitudes.
    for (int k = tid; k < NFREQ; k += 256) {
        const int nk = (1024 - k) & 1023;
        float2 Zk = X[PHYS(k)], Zn = X[PHYS(nk)];
        float ar = Zk.x + Zn.x, ai = Zk.y - Zn.y;
        float br = Zk.y + Zn.y, bi = Zn.x - Zk.x;
        spec0[k] = 0.5f * sqrtf(ar * ar + ai * ai);
        spec1[k] = 0.5f * sqrtf(br * br + bi * bi);
    }
    __syncthreads();

    // Sparse mel projection: column mm of fb is nonzero only on [a, c).
    const int pf = tid >> 7;
    const int mm = tid & 127;
    const float* sp = pf ? spec1 : spec0;
    const int a = bins.v[mm], bb = bins.v[mm + 1], c = bins.v[mm + 2];
    float acc = 0.f;
    if (bb > a) {
        float s = 0.f;
        for (int f = a; f < bb; f++) s = fmaf(sp[f], (float)(f - a), s);
        acc += s / (float)(bb - a);
    }
    if (c > bb) {
        float s = 0.f;
        for (int f = bb; f < c; f++) s = fmaf(sp[f], (float)(c - f), s);
        acc += s / (float)(c - bb);
    }
    mel[((size_t)b * NFRAMES + 2 * p + pf) * NMELS + mm] = acc;
}

// ---------------- Exact 3-phase PCEN ----------------
// EMA over a chunk is affine: M_out = D*M_in + S, D = 0.975^len,
// S = EMA-of-chunk-starting-from-zero. Phase 1 computes S per chunk,
// phase 2 scans chunks (exact M at each chunk boundary), phase 3 replays.

// Phase 1: S[b][c][m]. Thread -> (b, c, m), coalesced over m.
__global__ __launch_bounds__(256)
void pcen_sums(const float* __restrict__ mel, float* __restrict__ S) {
    const int idx  = blockIdx.x * 256 + threadIdx.x;
    const int m    = idx & 127;
    const int rest = idx >> 7;
    const int c    = rest % NCHUNK;
    const int b    = rest / NCHUNK;
    if (b >= NBATCH) return;

    const float* mp = mel + (size_t)b * NFRAMES * NMELS + m;
    const int t0 = c * PCEN_C;
    float s = 0.f;
    #pragma unroll
    for (int i = 0; i < PCEN_C; i++) {
        const int t = t0 + i;
        if (t >= NFRAMES) break;
        float v = mp[(size_t)t * NMELS];
        s = (t == 0) ? v : fmaf(0.975f, s, 0.025f * v);   // t=0: M = v0
    }
    S[((size_t)b * NCHUNK + c) * NMELS + m] = s;
}

// Phase 2: exclusive scan over chunks per (b,m): Mstart[c] = M entering chunk c.
__global__ __launch_bounds__(256)
void pcen_scan(const float* __restrict__ S, float* __restrict__ Mstart) {
    const int idx = blockIdx.x * 256 + threadIdx.x;   // 0..4095
    const int m = idx & 127;
    const int b = idx >> 7;
    if (b >= NBATCH) return;

    float D = 1.f;
    #pragma unroll
    for (int i = 0; i < PCEN_C; i++) D *= 0.975f;     // constant-folded

    const size_t base = (size_t)b * NCHUNK * NMELS + m;
    float M = 0.f;
    for (int c = 0; c < NCHUNK; c++) {
        Mstart[base + (size_t)c * NMELS] = M;
        float s = S[base + (size_t)c * NMELS];
        M = fmaf(D, M, s);
    }
}

// Phase 3: replay each chunk from exact Mstart, write outputs.
__global__ __launch_bounds__(256)
void pcen_out(const float* __restrict__ mel, const float* __restrict__ Mstart,
              float* __restrict__ out) {
    const int idx  = blockIdx.x * 256 + threadIdx.x;
    const int m    = idx & 127;
    const int rest = idx >> 7;
    const int c    = rest % NCHUNK;
    const int b    = rest / NCHUNK;
    if (b >= NBATCH) return;

    const float* mp = mel + (size_t)b * NFRAMES * NMELS + m;
    float*       op = out + (size_t)b * NFRAMES * NMELS + m;
    float M = Mstart[((size_t)b * NCHUNK + c) * NMELS + m];

    const int t0 = c * PCEN_C;
    #pragma unroll
    for (int i = 0; i < PCEN_C; i++) {
        const int t = t0 + i;
        if (t >= NFRAMES) break;
        float v = mp[(size_t)t * NMELS];
        M = (t == 0) ? v : fmaf(0.975f, M, 0.025f * v);
        float den = __powf(M + 1e-6f, 0.98f);
        op[(size_t)t * NMELS] = sqrtf(v / den + 2.0f) - 1.41421356237f;
    }
}

extern "C" void kernel_launch(void* const* d_in, const int* in_sizes, int n_in,
                              void* d_out, int out_size, void* d_ws, size_t ws_size,
                              hipStream_t stream) {
    const float* x  = (const float*)d_in[0];   // (32, 160000)
    float* out = (float*)d_out;                // (32, 626, 128)

    // Workspace carve-up (all 16B-aligned):
    float* mel    = (float*)d_ws;                              // 32*626*128 f32
    float* S      = mel + (size_t)NBATCH * NFRAMES * NMELS;    // 32*40*128 f32
    float* Mstart = S   + (size_t)NBATCH * NCHUNK * NMELS;     // 32*40*128 f32

    // Host-side bin edges, replicating numpy exactly in double.
    Bins bins;
    {
        const double m_max = 2595.0 * log10(1.0 + 8000.0 / 700.0);
        const double step  = m_max / 129.0;
        for (int i = 0; i < NMELS + 2; i++) {
            double mv = (i == NMELS + 1) ? m_max : (double)i * step;
            double f  = 700.0 * (pow(10.0, mv / 2595.0) - 1.0);
            bins.v[i] = (int)floor((double)(NFREQ - 1) * 2.0 * f / 16000.0);
        }
    }

    dim3 grid1(NPAIRS, NBATCH);
    fft_mel_kernel<<<grid1, 256, 0, stream>>>(x, mel, bins);

    const int nchunk_threads = NBATCH * NCHUNK * NMELS;   // 163840
    pcen_sums<<<(nchunk_threads + 255) / 256, 256, 0, stream>>>(mel, S);
    pcen_scan<<<(NBATCH * NMELS + 255) / 256, 256, 0, stream>>>(S, Mstart);
    pcen_out<<<(nchunk_threads + 255) / 256, 256, 0, stream>>>(mel, Mstart, out);
}